// Round 1
// baseline (66.984 us; speedup 1.0000x reference)
//
#include <hip/hip_runtime.h>
#include <math.h>

#define ND 64
#define NB 4
#define NPTS (NB * ND * ND * ND)   // 1,048,576

// gradU at one point: G[c][j] = d pred_c / d axis_j, jnp.gradient semantics
__device__ __forceinline__ void grad_at(const float* __restrict__ p,
                                        int b, int x, int y, int z,
                                        float G[3][3]) {
    // axis 0 = x
    {
        int tp = (x == ND - 1) ? x : x + 1;
        int tm = (x == 0) ? 0 : x - 1;
        float coef = (x == 0 || x == ND - 1) ? 1.0f : 0.5f;
        const float* pp = p + ((((size_t)(b * ND + tp) * ND + y) * ND + z) * 3);
        const float* pm = p + ((((size_t)(b * ND + tm) * ND + y) * ND + z) * 3);
#pragma unroll
        for (int c = 0; c < 3; c++) G[c][0] = coef * (pp[c] - pm[c]);
    }
    // axis 1 = y
    {
        int tp = (y == ND - 1) ? y : y + 1;
        int tm = (y == 0) ? 0 : y - 1;
        float coef = (y == 0 || y == ND - 1) ? 1.0f : 0.5f;
        const float* pp = p + ((((size_t)(b * ND + x) * ND + tp) * ND + z) * 3);
        const float* pm = p + ((((size_t)(b * ND + x) * ND + tm) * ND + z) * 3);
#pragma unroll
        for (int c = 0; c < 3; c++) G[c][1] = coef * (pp[c] - pm[c]);
    }
    // axis 2 = z
    {
        int tp = (z == ND - 1) ? z : z + 1;
        int tm = (z == 0) ? 0 : z - 1;
        float coef = (z == 0 || z == ND - 1) ? 1.0f : 0.5f;
        const float* pp = p + ((((size_t)(b * ND + x) * ND + y) * ND + tp) * 3);
        const float* pm = p + ((((size_t)(b * ND + x) * ND + y) * ND + tm) * 3);
#pragma unroll
        for (int c = 0; c < 3; c++) G[c][2] = coef * (pp[c] - pm[c]);
    }
}

__global__ __launch_bounds__(256) void phys_loss_kernel(
        const float* __restrict__ pred,
        const float* __restrict__ targ,
        float* __restrict__ out) {
    const int tid = blockIdx.x * blockDim.x + threadIdx.x;
    const int z = tid & 63;
    const int y = (tid >> 6) & 63;
    const int x = (tid >> 12) & 63;
    const int b = tid >> 18;

    // ---- gradU at center ----
    float G[3][3];
    grad_at(pred, b, x, y, z, G);

    // ---- hessU: H[c][j][k] = d G[c][j] / d axis_k (gradient of gradient) ----
    float H[3][3][3];
    {
        // axis k = 0 (x)
        {
            int tp = (x == ND - 1) ? x : x + 1;
            int tm = (x == 0) ? 0 : x - 1;
            float coef = (x == 0 || x == ND - 1) ? 1.0f : 0.5f;
            float Gp[3][3], Gm[3][3];
            grad_at(pred, b, tp, y, z, Gp);
            grad_at(pred, b, tm, y, z, Gm);
#pragma unroll
            for (int c = 0; c < 3; c++)
#pragma unroll
                for (int j = 0; j < 3; j++) H[c][j][0] = coef * (Gp[c][j] - Gm[c][j]);
        }
        // axis k = 1 (y)
        {
            int tp = (y == ND - 1) ? y : y + 1;
            int tm = (y == 0) ? 0 : y - 1;
            float coef = (y == 0 || y == ND - 1) ? 1.0f : 0.5f;
            float Gp[3][3], Gm[3][3];
            grad_at(pred, b, x, tp, z, Gp);
            grad_at(pred, b, x, tm, z, Gm);
#pragma unroll
            for (int c = 0; c < 3; c++)
#pragma unroll
                for (int j = 0; j < 3; j++) H[c][j][1] = coef * (Gp[c][j] - Gm[c][j]);
        }
        // axis k = 2 (z)
        {
            int tp = (z == ND - 1) ? z : z + 1;
            int tm = (z == 0) ? 0 : z - 1;
            float coef = (z == 0 || z == ND - 1) ? 1.0f : 0.5f;
            float Gp[3][3], Gm[3][3];
            grad_at(pred, b, x, y, tp, Gp);
            grad_at(pred, b, x, y, tm, Gm);
#pragma unroll
            for (int c = 0; c < 3; c++)
#pragma unroll
                for (int j = 0; j < 3; j++) H[c][j][2] = coef * (Gp[c][j] - Gm[c][j]);
        }
    }

    // ---- F = gradU + I ----
    float F[3][3];
#pragma unroll
    for (int c = 0; c < 3; c++)
#pragma unroll
        for (int j = 0; j < 3; j++) F[c][j] = G[c][j] + ((c == j) ? 1.0f : 0.0f);

    // ---- cofactor matrix ----
    float cof[3][3];
#pragma unroll
    for (int i = 0; i < 3; i++) {
        const int i1 = (i + 1) % 3, i2 = (i + 2) % 3;
#pragma unroll
        for (int j = 0; j < 3; j++) {
            const int j1 = (j + 1) % 3, j2 = (j + 2) % 3;
            cof[i][j] = F[i1][j1] * F[i2][j2] - F[i1][j2] * F[i2][j1];
        }
    }

    // ---- gradCofF[m][i][j] via product rule ----
    float gcof[3][3][3];
#pragma unroll
    for (int m = 0; m < 3; m++) {
        const int m1 = (m + 1) % 3, m2 = (m + 2) % 3;
#pragma unroll
        for (int i = 0; i < 3; i++) {
            const int i1 = (i + 1) % 3, i2 = (i + 2) % 3;
#pragma unroll
            for (int j = 0; j < 3; j++) {
                gcof[m][i][j] = F[m2][i2] * H[m1][i1][j] + F[m1][i1] * H[m2][i2][j]
                              - F[m2][i1] * H[m1][i2][j] - F[m1][i2] * H[m2][i1][j];
            }
        }
    }

    // ---- J, invJ, gradJ ----
    const float J = F[0][0] * cof[0][0] + F[1][0] * cof[1][0] + F[2][0] * cof[2][0] + 1e-8f;
    const float invJ = 1.0f / J;

    float gJ[3];
#pragma unroll
    for (int j = 0; j < 3; j++) {
        gJ[j] = cof[0][0] * H[0][0][j] + cof[1][0] * H[1][0][j] + cof[2][0] * H[2][0][j]
              + gcof[0][0][j] * F[0][0] + gcof[1][0][j] * F[1][0] + gcof[2][0][j] * F[2][0];
    }

    // ---- divPK1 ----
    const float MU = 1000.0f, LMBD = 5000.0f;
    const float halfL = 0.5f * LMBD * (J * J - 1.0f);
    float r[3];
#pragma unroll
    for (int m = 0; m < 3; m++) {
        const float s1 = gJ[0] * cof[m][0] + gJ[1] * cof[m][1] + gJ[2] * cof[m][2];
        const float tr = gcof[m][0][0] + gcof[m][1][1] + gcof[m][2][2];
        const float divInv = -invJ * invJ * s1 + invJ * tr;
        const float divF = H[m][0][0] + H[m][1][1] + H[m][2][2];
        float v = MU * (divF - divInv) + halfL * divInv + LMBD * s1;
        r[m] = (v != v) ? 0.0f : v;   // NaN -> 0
    }
    const float nrm = sqrtf(r[0] * r[0] + r[1] * r[1] + r[2] * r[2]);

    // ---- MSE contribution ----
    const float* pp = pred + (size_t)tid * 3;
    const float* tt = targ + (size_t)tid * 3;
    float ssq = 0.0f;
#pragma unroll
    for (int c = 0; c < 3; c++) {
        const float d = pp[c] - tt[c];
        ssq += d * d;
    }

    const float invN = 1.0f / (float)NPTS;
    float val = 0.5f * ssq * (invN * (1.0f / 3.0f)) + 0.5f * nrm * invN;

    // ---- block reduction: wave shuffle, then LDS across 4 waves ----
#pragma unroll
    for (int off = 32; off > 0; off >>= 1) val += __shfl_down(val, off, 64);

    __shared__ float wsum[4];
    const int lane = threadIdx.x & 63;
    const int wid = threadIdx.x >> 6;
    if (lane == 0) wsum[wid] = val;
    __syncthreads();
    if (threadIdx.x == 0) {
        atomicAdd(out, wsum[0] + wsum[1] + wsum[2] + wsum[3]);
    }
}

extern "C" void kernel_launch(void* const* d_in, const int* in_sizes, int n_in,
                              void* d_out, int out_size, void* d_ws, size_t ws_size,
                              hipStream_t stream) {
    const float* pred = (const float*)d_in[0];
    const float* targ = (const float*)d_in[1];
    float* out = (float*)d_out;

    hipMemsetAsync(out, 0, sizeof(float), stream);

    const int threads = 256;
    const int blocks = NPTS / threads;  // 4096
    phys_loss_kernel<<<blocks, threads, 0, stream>>>(pred, targ, out);
}

// Round 2
// 53.018 us; speedup vs baseline: 1.2634x; 1.2634x over previous
//
#include <hip/hip_runtime.h>
#include <math.h>

#define ND 64
#define NB 4
#define NPTS (NB * ND * ND * ND)   // 1,048,576

// LDS tile: 8^3 points + halo 2 -> 12^3 points, float3 each.
// float-unit strides within the tile:
#define SX 432   // 12*12*3
#define SY 36    // 12*3
#define SZ 3

// gradient (jnp.gradient semantics) read from the LDS tile.
// base = float index of the point in the tile; (pgx,pgy,pgz) = global coords
// (needed for edge-clamp coefficients).
__device__ __forceinline__ void grad_lds(const float* __restrict__ s, int base,
                                         int pgx, int pgy, int pgz,
                                         float G[3][3]) {
    const int dxp = (pgx == ND - 1) ? 0 : SX, dxm = (pgx == 0) ? 0 : SX;
    const float cx = (pgx == 0 || pgx == ND - 1) ? 1.0f : 0.5f;
    const int dyp = (pgy == ND - 1) ? 0 : SY, dym = (pgy == 0) ? 0 : SY;
    const float cy = (pgy == 0 || pgy == ND - 1) ? 1.0f : 0.5f;
    const int dzp = (pgz == ND - 1) ? 0 : SZ, dzm = (pgz == 0) ? 0 : SZ;
    const float cz = (pgz == 0 || pgz == ND - 1) ? 1.0f : 0.5f;
#pragma unroll
    for (int c = 0; c < 3; c++) {
        G[c][0] = cx * (s[base + dxp + c] - s[base - dxm + c]);
        G[c][1] = cy * (s[base + dyp + c] - s[base - dym + c]);
        G[c][2] = cz * (s[base + dzp + c] - s[base - dzm + c]);
    }
}

__global__ __launch_bounds__(512) void phys_loss_kernel(
        const float* __restrict__ pred,
        const float* __restrict__ targ,
        float* __restrict__ out) {
    __shared__ float s[12 * 12 * 12 * 3];   // 20736 B

    const int bid = blockIdx.x;
    const int zt = bid & 7, yt = (bid >> 3) & 7, xt = (bid >> 6) & 7, b = bid >> 9;
    const int t = threadIdx.x;
    const int tz = t & 7, ty = (t >> 3) & 7, tx = t >> 6;

    // ---- stage pred tile (halo 2, clamped) into LDS ----
    const int X0 = xt * 8 - 2, Y0 = yt * 8 - 2, Z0 = zt * 8 - 2;
    for (int i = t; i < 12 * 12 * 12; i += 512) {
        const int lz = i % 12;
        const int tmp = i / 12;
        const int ly = tmp % 12;
        const int lx = tmp / 12;
        const int ggx = min(max(X0 + lx, 0), ND - 1);
        const int ggy = min(max(Y0 + ly, 0), ND - 1);
        const int ggz = min(max(Z0 + lz, 0), ND - 1);
        const float* g = pred + (size_t)(((b * ND + ggx) * ND + ggy) * ND + ggz) * 3;
        const int o = i * 3;
        s[o]     = g[0];
        s[o + 1] = g[1];
        s[o + 2] = g[2];
    }
    __syncthreads();

    const int gx = xt * 8 + tx, gy = yt * 8 + ty, gz = zt * 8 + tz;
    const int base = (((tx + 2) * 12 + (ty + 2)) * 12 + (tz + 2)) * 3;

    // step flags (0 at the clamped edge, 1 otherwise)
    const int sxp = (gx == ND - 1) ? 0 : 1, sxm = (gx == 0) ? 0 : 1;
    const int syp = (gy == ND - 1) ? 0 : 1, sym = (gy == 0) ? 0 : 1;
    const int szp = (gz == ND - 1) ? 0 : 1, szm = (gz == 0) ? 0 : 1;

    // ---- gradU at center ----
    float G[3][3];
    grad_lds(s, base, gx, gy, gz, G);

    // ---- hessU: H[c][j][k] = d G[c][j] / d axis_k ----
    float H[3][3][3];
    {   // k = 0 (x)
        const float cH = (sxp & sxm) ? 0.5f : 1.0f;
        float Gp[3][3], Gm[3][3];
        grad_lds(s, base + sxp * SX, gx + sxp, gy, gz, Gp);
        grad_lds(s, base - sxm * SX, gx - sxm, gy, gz, Gm);
#pragma unroll
        for (int c = 0; c < 3; c++)
#pragma unroll
            for (int j = 0; j < 3; j++) H[c][j][0] = cH * (Gp[c][j] - Gm[c][j]);
    }
    {   // k = 1 (y)
        const float cH = (syp & sym) ? 0.5f : 1.0f;
        float Gp[3][3], Gm[3][3];
        grad_lds(s, base + syp * SY, gx, gy + syp, gz, Gp);
        grad_lds(s, base - sym * SY, gx, gy - sym, gz, Gm);
#pragma unroll
        for (int c = 0; c < 3; c++)
#pragma unroll
            for (int j = 0; j < 3; j++) H[c][j][1] = cH * (Gp[c][j] - Gm[c][j]);
    }
    {   // k = 2 (z)
        const float cH = (szp & szm) ? 0.5f : 1.0f;
        float Gp[3][3], Gm[3][3];
        grad_lds(s, base + szp * SZ, gx, gy, gz + szp, Gp);
        grad_lds(s, base - szm * SZ, gx, gy, gz - szm, Gm);
#pragma unroll
        for (int c = 0; c < 3; c++)
#pragma unroll
            for (int j = 0; j < 3; j++) H[c][j][2] = cH * (Gp[c][j] - Gm[c][j]);
    }

    // ---- F = gradU + I ----
    float F[3][3];
#pragma unroll
    for (int c = 0; c < 3; c++)
#pragma unroll
        for (int j = 0; j < 3; j++) F[c][j] = G[c][j] + ((c == j) ? 1.0f : 0.0f);

    // ---- cofactor matrix ----
    float cof[3][3];
#pragma unroll
    for (int i = 0; i < 3; i++) {
        const int i1 = (i + 1) % 3, i2 = (i + 2) % 3;
#pragma unroll
        for (int j = 0; j < 3; j++) {
            const int j1 = (j + 1) % 3, j2 = (j + 2) % 3;
            cof[i][j] = F[i1][j1] * F[i2][j2] - F[i1][j2] * F[i2][j1];
        }
    }

    // ---- gradCofF: only gcof[m][0][j] and trace gcof[m][i][i] are consumed ----
    float gc0[3][3], trg[3];
#pragma unroll
    for (int m = 0; m < 3; m++) {
        const int m1 = (m + 1) % 3, m2 = (m + 2) % 3;
        trg[m] = 0.0f;
#pragma unroll
        for (int i = 0; i < 3; i++) {
            const int i1 = (i + 1) % 3, i2 = (i + 2) % 3;
#pragma unroll
            for (int j = 0; j < 3; j++) {
                if (i == 0 || i == j) {
                    const float g = F[m2][i2] * H[m1][i1][j] + F[m1][i1] * H[m2][i2][j]
                                  - F[m2][i1] * H[m1][i2][j] - F[m1][i2] * H[m2][i1][j];
                    if (i == 0) gc0[m][j] = g;
                    if (i == j) trg[m] += g;
                }
            }
        }
    }

    // ---- J, invJ, gradJ ----
    const float J = F[0][0] * cof[0][0] + F[1][0] * cof[1][0] + F[2][0] * cof[2][0] + 1e-8f;
    const float invJ = 1.0f / J;

    float gJ[3];
#pragma unroll
    for (int j = 0; j < 3; j++) {
        gJ[j] = cof[0][0] * H[0][0][j] + cof[1][0] * H[1][0][j] + cof[2][0] * H[2][0][j]
              + gc0[0][j] * F[0][0] + gc0[1][j] * F[1][0] + gc0[2][j] * F[2][0];
    }

    // ---- divPK1 ----
    const float MU = 1000.0f, LMBD = 5000.0f;
    const float halfL = 0.5f * LMBD * (J * J - 1.0f);
    float r[3];
#pragma unroll
    for (int m = 0; m < 3; m++) {
        const float s1 = gJ[0] * cof[m][0] + gJ[1] * cof[m][1] + gJ[2] * cof[m][2];
        const float divInv = -invJ * invJ * s1 + invJ * trg[m];
        const float divF = H[m][0][0] + H[m][1][1] + H[m][2][2];
        float v = MU * (divF - divInv) + halfL * divInv + LMBD * s1;
        r[m] = (v != v) ? 0.0f : v;   // NaN -> 0
    }
    const float nrm = sqrtf(r[0] * r[0] + r[1] * r[1] + r[2] * r[2]);

    // ---- MSE contribution (pred from LDS, targ from global) ----
    const size_t pidx = (size_t)(((b * ND + gx) * ND + gy) * ND + gz) * 3;
    const float* tt = targ + pidx;
    float ssq = 0.0f;
#pragma unroll
    for (int c = 0; c < 3; c++) {
        const float d = s[base + c] - tt[c];
        ssq += d * d;
    }

    const float invN = 1.0f / (float)NPTS;
    float val = 0.5f * ssq * (invN * (1.0f / 3.0f)) + 0.5f * nrm * invN;

    // ---- reduction: wave shuffle, then LDS across 8 waves ----
#pragma unroll
    for (int off = 32; off > 0; off >>= 1) val += __shfl_down(val, off, 64);

    __shared__ float wsum[8];
    const int lane = t & 63;
    const int wid = t >> 6;
    if (lane == 0) wsum[wid] = val;
    __syncthreads();
    if (t == 0) {
        float acc = 0.0f;
#pragma unroll
        for (int w = 0; w < 8; w++) acc += wsum[w];
        atomicAdd(out, acc);
    }
}

extern "C" void kernel_launch(void* const* d_in, const int* in_sizes, int n_in,
                              void* d_out, int out_size, void* d_ws, size_t ws_size,
                              hipStream_t stream) {
    const float* pred = (const float*)d_in[0];
    const float* targ = (const float*)d_in[1];
    float* out = (float*)d_out;

    hipMemsetAsync(out, 0, sizeof(float), stream);

    const int blocks = NB * 8 * 8 * 8;   // 2048
    phys_loss_kernel<<<blocks, 512, 0, stream>>>(pred, targ, out);
}

// Round 3
// 43.481 us; speedup vs baseline: 1.5405x; 1.2193x over previous
//
#include <hip/hip_runtime.h>
#include <math.h>

#define ND 64
#define NPTS (4 * ND * ND * ND)   // 1,048,576

// LDS tile: 8^3 owned + halo 2 -> 12^3 float3, AoS, dword strides:
#define SX 432   // 12*12*3
#define SY 36    // 12*3
#define SZ 3

__global__ __launch_bounds__(512) void phys_loss_kernel(
        const float* __restrict__ pred,
        const float* __restrict__ targ,
        float* __restrict__ out) {
    __shared__ float s[12 * 12 * 12 * 3];   // 20736 B

    const int bid = blockIdx.x;
    const int zt = bid & 7, yt = (bid >> 3) & 7, xt = (bid >> 6) & 7, b = bid >> 9;
    const int t = threadIdx.x;
    const int tz = t & 7, ty = (t >> 3) & 7, tx = t >> 6;
    const int X0 = xt * 8 - 2, Y0 = yt * 8 - 2, Z0 = zt * 8 - 2;

    // ---- pass A: clamped fill of the whole 12^3 tile ----
    for (int i = t; i < 1728; i += 512) {
        const int lz = i % 12;
        const int tmp = i / 12;
        const int ly = tmp % 12;
        const int lx = tmp / 12;
        const int gx = min(max(X0 + lx, 0), ND - 1);
        const int gy = min(max(Y0 + ly, 0), ND - 1);
        const int gz = min(max(Z0 + lz, 0), ND - 1);
        const float* g = pred + (size_t)(((b * ND + gx) * ND + gy) * ND + gz) * 3;
        const int o = i * 3;
        s[o] = g[0]; s[o + 1] = g[1]; s[o + 2] = g[2];
    }
    __syncthreads();

    // ---- pass B: x ghost planes (linear/quadratic extrapolation) ----
    // depth1: t[e+sg]  = 2 t[e] - t[e-sg]
    // depth2: t[e+2sg] = 4 t[e] - 4 t[e-sg] + t[e-2sg]
    if (xt == 0 || xt == 7) {
        const int e = (xt == 0) ? 2 : 9, sg = (xt == 0) ? -1 : 1;
        for (int i = t; i < 864; i += 512) {
            const int c = i % 3;
            const int r = i / 3;
            const int lz = r % 12, ly = (r / 12) % 12, pl = r / 144;
            const int rowo = ly * SY + lz * SZ + c;
            const float te = s[e * SX + rowo];
            const float n1 = s[(e - sg) * SX + rowo];
            if (pl == 0) {
                s[(e + sg) * SX + rowo] = 2.0f * te - n1;
            } else {
                const float n2 = s[(e - 2 * sg) * SX + rowo];
                s[(e + 2 * sg) * SX + rowo] = 4.0f * te - 4.0f * n1 + n2;
            }
        }
    }
    __syncthreads();

    // ---- pass C: y ghost planes ----
    if (yt == 0 || yt == 7) {
        const int e = (yt == 0) ? 2 : 9, sg = (yt == 0) ? -1 : 1;
        for (int i = t; i < 864; i += 512) {
            const int c = i % 3;
            const int r = i / 3;
            const int lz = r % 12, lx = (r / 12) % 12, pl = r / 144;
            const int rowo = lx * SX + lz * SZ + c;
            const float te = s[e * SY + rowo];
            const float n1 = s[(e - sg) * SY + rowo];
            if (pl == 0) {
                s[(e + sg) * SY + rowo] = 2.0f * te - n1;
            } else {
                const float n2 = s[(e - 2 * sg) * SY + rowo];
                s[(e + 2 * sg) * SY + rowo] = 4.0f * te - 4.0f * n1 + n2;
            }
        }
    }
    __syncthreads();

    // ---- pass D: z ghost planes ----
    if (zt == 0 || zt == 7) {
        const int e = (zt == 0) ? 2 : 9, sg = (zt == 0) ? -1 : 1;
        for (int i = t; i < 864; i += 512) {
            const int c = i % 3;
            const int r = i / 3;
            const int ly = r % 12, lx = (r / 12) % 12, pl = r / 144;
            const int rowo = lx * SX + ly * SY + c;
            const float te = s[e * SZ + rowo];
            const float n1 = s[(e - sg) * SZ + rowo];
            if (pl == 0) {
                s[(e + sg) * SZ + rowo] = 2.0f * te - n1;
            } else {
                const float n2 = s[(e - 2 * sg) * SZ + rowo];
                s[(e + 2 * sg) * SZ + rowo] = 4.0f * te - 4.0f * n1 + n2;
            }
        }
    }
    __syncthreads();

    // ---- uniform central-difference stencil (25-point footprint) ----
    const int base = (((tx + 2) * 12 + (ty + 2)) * 12 + (tz + 2)) * 3;

#define LD3(name, dx, dy, dz) \
    float name[3]; { const int o_ = base + (dx) * SX + (dy) * SY + (dz) * SZ; \
        name[0] = s[o_]; name[1] = s[o_ + 1]; name[2] = s[o_ + 2]; }

    LD3(c0, 0, 0, 0)
    LD3(px, 1, 0, 0)   LD3(mx, -1, 0, 0)
    LD3(py, 0, 1, 0)   LD3(my, 0, -1, 0)
    LD3(pz, 0, 0, 1)   LD3(mz, 0, 0, -1)
    LD3(px2, 2, 0, 0)  LD3(mx2, -2, 0, 0)
    LD3(py2, 0, 2, 0)  LD3(my2, 0, -2, 0)
    LD3(pz2, 0, 0, 2)  LD3(mz2, 0, 0, -2)
    LD3(pxpy, 1, 1, 0)  LD3(pxmy, 1, -1, 0)  LD3(mxpy, -1, 1, 0)  LD3(mxmy, -1, -1, 0)
    LD3(pxpz, 1, 0, 1)  LD3(pxmz, 1, 0, -1)  LD3(mxpz, -1, 0, 1)  LD3(mxmz, -1, 0, -1)
    LD3(pypz, 0, 1, 1)  LD3(pymz, 0, 1, -1)  LD3(mypz, 0, -1, 1)  LD3(mymz, 0, -1, -1)
#undef LD3

    float F[3][3], H[3][3][3];
#pragma unroll
    for (int c = 0; c < 3; c++) {
        F[c][0] = 0.5f * (px[c] - mx[c]) + ((c == 0) ? 1.0f : 0.0f);
        F[c][1] = 0.5f * (py[c] - my[c]) + ((c == 1) ? 1.0f : 0.0f);
        F[c][2] = 0.5f * (pz[c] - mz[c]) + ((c == 2) ? 1.0f : 0.0f);
        H[c][0][0] = 0.25f * (px2[c] + mx2[c]) - 0.5f * c0[c];
        H[c][1][1] = 0.25f * (py2[c] + my2[c]) - 0.5f * c0[c];
        H[c][2][2] = 0.25f * (pz2[c] + mz2[c]) - 0.5f * c0[c];
        const float hxy = 0.25f * ((pxpy[c] - mxpy[c]) - (pxmy[c] - mxmy[c]));
        const float hxz = 0.25f * ((pxpz[c] - mxpz[c]) - (pxmz[c] - mxmz[c]));
        const float hyz = 0.25f * ((pypz[c] - mypz[c]) - (pymz[c] - mymz[c]));
        H[c][0][1] = hxy; H[c][1][0] = hxy;
        H[c][0][2] = hxz; H[c][2][0] = hxz;
        H[c][1][2] = hyz; H[c][2][1] = hyz;
    }

    // ---- cofactor matrix ----
    float cof[3][3];
#pragma unroll
    for (int i = 0; i < 3; i++) {
        const int i1 = (i + 1) % 3, i2 = (i + 2) % 3;
#pragma unroll
        for (int j = 0; j < 3; j++) {
            const int j1 = (j + 1) % 3, j2 = (j + 2) % 3;
            cof[i][j] = F[i1][j1] * F[i2][j2] - F[i1][j2] * F[i2][j1];
        }
    }

    // ---- gradCofF: only gcof[m][0][j] and the trace are consumed ----
    float gc0[3][3], trg[3];
#pragma unroll
    for (int m = 0; m < 3; m++) {
        const int m1 = (m + 1) % 3, m2 = (m + 2) % 3;
        trg[m] = 0.0f;
#pragma unroll
        for (int i = 0; i < 3; i++) {
            const int i1 = (i + 1) % 3, i2 = (i + 2) % 3;
#pragma unroll
            for (int j = 0; j < 3; j++) {
                if (i == 0 || i == j) {
                    const float g = F[m2][i2] * H[m1][i1][j] + F[m1][i1] * H[m2][i2][j]
                                  - F[m2][i1] * H[m1][i2][j] - F[m1][i2] * H[m2][i1][j];
                    if (i == 0) gc0[m][j] = g;
                    if (i == j) trg[m] += g;
                }
            }
        }
    }

    // ---- J, invJ, gradJ ----
    const float J = F[0][0] * cof[0][0] + F[1][0] * cof[1][0] + F[2][0] * cof[2][0] + 1e-8f;
    const float invJ = 1.0f / J;

    float gJ[3];
#pragma unroll
    for (int j = 0; j < 3; j++) {
        gJ[j] = cof[0][0] * H[0][0][j] + cof[1][0] * H[1][0][j] + cof[2][0] * H[2][0][j]
              + gc0[0][j] * F[0][0] + gc0[1][j] * F[1][0] + gc0[2][j] * F[2][0];
    }

    // ---- divPK1 ----
    const float MU = 1000.0f, LMBD = 5000.0f;
    const float halfL = 0.5f * LMBD * (J * J - 1.0f);
    float r[3];
#pragma unroll
    for (int m = 0; m < 3; m++) {
        const float s1 = gJ[0] * cof[m][0] + gJ[1] * cof[m][1] + gJ[2] * cof[m][2];
        const float divInv = -invJ * invJ * s1 + invJ * trg[m];
        const float divF = H[m][0][0] + H[m][1][1] + H[m][2][2];
        float v = MU * (divF - divInv) + halfL * divInv + LMBD * s1;
        r[m] = (v != v) ? 0.0f : v;   // NaN -> 0
    }
    const float nrm = sqrtf(r[0] * r[0] + r[1] * r[1] + r[2] * r[2]);

    // ---- MSE contribution (pred center from LDS regs, targ from global) ----
    const int gx = xt * 8 + tx, gy = yt * 8 + ty, gz = zt * 8 + tz;
    const size_t pidx = (size_t)(((b * ND + gx) * ND + gy) * ND + gz) * 3;
    const float* tt = targ + pidx;
    float ssq = 0.0f;
#pragma unroll
    for (int c = 0; c < 3; c++) {
        const float d = c0[c] - tt[c];
        ssq += d * d;
    }

    const float invN = 1.0f / (float)NPTS;
    float val = 0.5f * ssq * (invN * (1.0f / 3.0f)) + 0.5f * nrm * invN;

    // ---- reduction: wave shuffle, then LDS across 8 waves ----
#pragma unroll
    for (int off = 32; off > 0; off >>= 1) val += __shfl_down(val, off, 64);

    __shared__ float wsum[8];
    const int lane = t & 63;
    const int wid = t >> 6;
    if (lane == 0) wsum[wid] = val;
    __syncthreads();
    if (t == 0) {
        float acc = 0.0f;
#pragma unroll
        for (int w = 0; w < 8; w++) acc += wsum[w];
        atomicAdd(out, acc);
    }
}

extern "C" void kernel_launch(void* const* d_in, const int* in_sizes, int n_in,
                              void* d_out, int out_size, void* d_ws, size_t ws_size,
                              hipStream_t stream) {
    const float* pred = (const float*)d_in[0];
    const float* targ = (const float*)d_in[1];
    float* out = (float*)d_out;

    hipMemsetAsync(out, 0, sizeof(float), stream);

    const int blocks = 4 * 8 * 8 * 8;   // 2048
    phys_loss_kernel<<<blocks, 512, 0, stream>>>(pred, targ, out);
}